// Round 2
// baseline (75.653 us; speedup 1.0000x reference)
//
#include <hip/hip_runtime.h>
#include <cstdint>
#include <cstddef>

// Problem constants (from reference)
constexpr int N    = 50000;   // library size
constexpr int D    = 768;     // vision dim
constexpr int OD   = 384;     // option / answer dim
constexpr int TOPK = 25;

// K1 config: one 64-lane wave per row
constexpr int K1_BLOCKS  = 2048;
constexpr int K1_THREADS = 256;                       // 4 waves
constexpr int WAVES_TOTAL = K1_BLOCKS * (K1_THREADS / 64); // 8192

// top-k phase-1 config
constexpr int TK_BLOCKS = 64;
constexpr int TK_CHUNK  = 784;    // 64 * 784 = 50176 >= 50000
constexpr int NCAND     = TK_BLOCKS * TOPK;  // 1600

// ---------------------------------------------------------------------------
// K1: per-row cosine score s[n] = clip(dot(v,f_n)/(|v||f_n|), 0, 1),
//     plus per-block partial sums of exp(s[n]) (softmax denominator).
// One wave per row; row reads are 3 KB contiguous (fully coalesced float4).
// ---------------------------------------------------------------------------
__global__ __launch_bounds__(K1_THREADS)
void k_scores(const float* __restrict__ v,
              const float* __restrict__ n_feats,
              float* __restrict__ s_out,
              float* __restrict__ part_out)
{
    const int lane  = threadIdx.x & 63;
    const int wib   = threadIdx.x >> 6;           // wave in block (0..3)
    const int gwave = blockIdx.x * 4 + wib;       // global wave id

    const float4* v4 = reinterpret_cast<const float4*>(v);
    const float4 va = v4[lane];
    const float4 vb = v4[lane + 64];
    const float4 vc = v4[lane + 128];

    // |v| (identical result in every lane after butterfly)
    float vsq = 0.f;
    vsq = fmaf(va.x, va.x, vsq); vsq = fmaf(va.y, va.y, vsq);
    vsq = fmaf(va.z, va.z, vsq); vsq = fmaf(va.w, va.w, vsq);
    vsq = fmaf(vb.x, vb.x, vsq); vsq = fmaf(vb.y, vb.y, vsq);
    vsq = fmaf(vb.z, vb.z, vsq); vsq = fmaf(vb.w, vb.w, vsq);
    vsq = fmaf(vc.x, vc.x, vsq); vsq = fmaf(vc.y, vc.y, vsq);
    vsq = fmaf(vc.z, vc.z, vsq); vsq = fmaf(vc.w, vc.w, vsq);
    #pragma unroll
    for (int off = 32; off; off >>= 1) vsq += __shfl_xor(vsq, off);
    const float inv_vn = 1.0f / fmaxf(sqrtf(vsq), 1e-12f);

    float esum = 0.f;
    for (int r = gwave; r < N; r += WAVES_TOTAL) {
        const float4* f4 = reinterpret_cast<const float4*>(n_feats + (size_t)r * D);
        const float4 a0 = f4[lane];
        const float4 a1 = f4[lane + 64];
        const float4 a2 = f4[lane + 128];

        float dot = 0.f, nsq = 0.f;
        dot = fmaf(a0.x, va.x, dot); nsq = fmaf(a0.x, a0.x, nsq);
        dot = fmaf(a0.y, va.y, dot); nsq = fmaf(a0.y, a0.y, nsq);
        dot = fmaf(a0.z, va.z, dot); nsq = fmaf(a0.z, a0.z, nsq);
        dot = fmaf(a0.w, va.w, dot); nsq = fmaf(a0.w, a0.w, nsq);
        dot = fmaf(a1.x, vb.x, dot); nsq = fmaf(a1.x, a1.x, nsq);
        dot = fmaf(a1.y, vb.y, dot); nsq = fmaf(a1.y, a1.y, nsq);
        dot = fmaf(a1.z, vb.z, dot); nsq = fmaf(a1.z, a1.z, nsq);
        dot = fmaf(a1.w, vb.w, dot); nsq = fmaf(a1.w, a1.w, nsq);
        dot = fmaf(a2.x, vc.x, dot); nsq = fmaf(a2.x, a2.x, nsq);
        dot = fmaf(a2.y, vc.y, dot); nsq = fmaf(a2.y, a2.y, nsq);
        dot = fmaf(a2.z, vc.z, dot); nsq = fmaf(a2.z, a2.z, nsq);
        dot = fmaf(a2.w, vc.w, dot); nsq = fmaf(a2.w, a2.w, nsq);

        #pragma unroll
        for (int off = 32; off; off >>= 1) {
            dot += __shfl_xor(dot, off);
            nsq += __shfl_xor(nsq, off);
        }

        float s = dot * inv_vn / fmaxf(sqrtf(nsq), 1e-12f);
        s = fminf(fmaxf(s, 0.f), 1.f);
        if (lane == 0) s_out[r] = s;
        esum += expf(s);   // identical in all lanes; we only use lane 0's copy
    }

    __shared__ float wsum[4];
    if (lane == 0) wsum[wib] = esum;
    __syncthreads();
    if (threadIdx.x == 0)
        part_out[blockIdx.x] = (wsum[0] + wsum[1]) + (wsum[2] + wsum[3]);
}

// ---------------------------------------------------------------------------
// K2: per-chunk exact top-25 candidates. Key packs (value_bits << 32) | (~idx)
// so larger value wins, ties broken by LOWER index (matches jax.lax.top_k).
// s >= 0 (clipped) so raw float bits are integer-ordered.
// ---------------------------------------------------------------------------
__global__ __launch_bounds__(256)
void k_topk1(const float* __restrict__ s_in,
             unsigned long long* __restrict__ cand)
{
    __shared__ unsigned long long keys[TK_CHUNK];
    __shared__ unsigned long long wbest[4];
    __shared__ int wpos[4];

    const int b    = blockIdx.x;
    const int base = b * TK_CHUNK;
    const int lane = threadIdx.x & 63;
    const int wib  = threadIdx.x >> 6;

    for (int i = threadIdx.x; i < TK_CHUNK; i += 256) {
        const int g = base + i;
        unsigned long long key = 0ull;
        if (g < N) {
            const unsigned int bits = __float_as_uint(s_in[g]);
            key = ((unsigned long long)bits << 32) |
                  (unsigned long long)(0xFFFFFFFFu - (unsigned)g);
        }
        keys[i] = key;
    }
    __syncthreads();

    for (int round = 0; round < TOPK; ++round) {
        unsigned long long best = 0ull; int bestpos = -1;
        for (int i = threadIdx.x; i < TK_CHUNK; i += 256) {
            const unsigned long long k = keys[i];
            if (k > best) { best = k; bestpos = i; }
        }
        #pragma unroll
        for (int off = 32; off; off >>= 1) {
            const unsigned long long ok = __shfl_xor(best, off);
            const int op = __shfl_xor(bestpos, off);
            if (ok > best) { best = ok; bestpos = op; }
        }
        if (lane == 0) { wbest[wib] = best; wpos[wib] = bestpos; }
        __syncthreads();
        if (threadIdx.x == 0) {
            for (int w = 1; w < 4; ++w)
                if (wbest[w] > best) { best = wbest[w]; bestpos = wpos[w]; }
            cand[b * TOPK + round] = best;
            if (bestpos >= 0) keys[bestpos] = 0ull;
        }
        __syncthreads();
    }
}

// ---------------------------------------------------------------------------
// K3: single block (384 threads). (a) reduce Z from partials, (b) merge 1600
// candidates to the exact global top-25, (c) oia = sum_j w_j * n_answ[idx_j],
// (d) 3 dots.
// Reduction note: 384 = 3*128 has an odd factor, so a naive s>>=1 tree DROPS
// red[2] at the s=3 step (this was the round-1 bug: Z came out 2/3 of true and
// the final dots lost 1/3 of their terms). Fix: explicit 384->256 collapse,
// then a power-of-2 tree.
// ---------------------------------------------------------------------------
__global__ __launch_bounds__(384)
void k_final(const float* __restrict__ part,
             const unsigned long long* __restrict__ cand,
             const float* __restrict__ n_answ,
             const float* __restrict__ o,
             const float* __restrict__ temp_vid,
             float* __restrict__ out)
{
    __shared__ unsigned long long keys[NCAND];
    __shared__ float red[384];
    __shared__ float topw[TOPK];
    __shared__ int   topi[TOPK];
    __shared__ unsigned long long wb[6];
    __shared__ int wp[6];
    __shared__ float zsh;

    const int tid  = threadIdx.x;
    const int lane = tid & 63;
    const int wib  = tid >> 6;

    // (a) softmax denominator Z (deterministic tree, 384->256->pow2)
    float z = 0.f;
    for (int i = tid; i < K1_BLOCKS; i += 384) z += part[i];
    red[tid] = z;
    __syncthreads();
    if (tid < 128) red[tid] += red[tid + 256];
    __syncthreads();
    for (int s = 128; s > 0; s >>= 1) {
        if (tid < s) red[tid] += red[tid + s];
        __syncthreads();
    }
    if (tid == 0) zsh = red[0];

    // (b) load candidates, extract top-25
    for (int i = tid; i < NCAND; i += 384) keys[i] = cand[i];
    __syncthreads();

    for (int round = 0; round < TOPK; ++round) {
        unsigned long long best = 0ull; int bestpos = -1;
        for (int i = tid; i < NCAND; i += 384) {
            const unsigned long long k = keys[i];
            if (k > best) { best = k; bestpos = i; }
        }
        #pragma unroll
        for (int off = 32; off; off >>= 1) {
            const unsigned long long ok = __shfl_xor(best, off);
            const int op = __shfl_xor(bestpos, off);
            if (ok > best) { best = ok; bestpos = op; }
        }
        if (lane == 0) { wb[wib] = best; wp[wib] = bestpos; }
        __syncthreads();
        if (tid == 0) {
            for (int w = 1; w < 6; ++w)
                if (wb[w] > best) { best = wb[w]; bestpos = wp[w]; }
            const float sv = __uint_as_float((unsigned)(best >> 32));
            const int  idx = (int)(0xFFFFFFFFu - (unsigned)(best & 0xFFFFFFFFu));
            topw[round] = expf(sv);
            topi[round] = idx;
            if (bestpos >= 0) keys[bestpos] = 0ull;
        }
        __syncthreads();
    }

    // (c) weights: attention_j = exp(s_j)/Z * vid_gate;  vid_gate = 2*sigmoid(t)
    const float gate = 2.f / (1.f + expf(-temp_vid[0]));
    const float scale = gate / zsh;

    float oia = 0.f;
    if (tid < OD) {
        #pragma unroll
        for (int j = 0; j < TOPK; ++j)
            oia = fmaf(topw[j] * scale, n_answ[(size_t)topi[j] * OD + tid], oia);
    }

    // (d) scores[k] = sum_d oia[d] * o[k][d]  (384->256->pow2 tree)
    for (int k = 0; k < 3; ++k) {
        red[tid] = (tid < OD) ? oia * o[k * OD + tid] : 0.f;
        __syncthreads();
        if (tid < 128) red[tid] += red[tid + 256];
        __syncthreads();
        for (int s = 128; s > 0; s >>= 1) {
            if (tid < s) red[tid] += red[tid + s];
            __syncthreads();
        }
        if (tid == 0) out[k] = red[0];
        __syncthreads();
    }
}

// ---------------------------------------------------------------------------
extern "C" void kernel_launch(void* const* d_in, const int* in_sizes, int n_in,
                              void* d_out, int out_size, void* d_ws, size_t ws_size,
                              hipStream_t stream)
{
    // setup_inputs order:
    // 0 v, 1 n_feats, 2 aud, 3 n_auds, 4 ocr, 5 n_ocrs, 6 o, 7 n_answ,
    // 8 temp_vid, 9 temp_aud, 10 temp_ocr
    const float* v        = (const float*)d_in[0];
    const float* n_feats  = (const float*)d_in[1];
    const float* o        = (const float*)d_in[6];
    const float* n_answ   = (const float*)d_in[7];
    const float* temp_vid = (const float*)d_in[8];
    // aud/ocr branches are multiplied by exactly 0.0 in the reference -> skipped.
    float* out = (float*)d_out;

    char* ws = (char*)d_ws;
    float* ws_s                  = (float*)(ws);            // 50000 f32 = 200000 B
    float* ws_part               = (float*)(ws + 204800);   // 2048 f32  = 8192 B
    unsigned long long* ws_cand  = (unsigned long long*)(ws + 215040); // 1600 u64 = 12800 B

    k_scores<<<K1_BLOCKS, K1_THREADS, 0, stream>>>(v, n_feats, ws_s, ws_part);
    k_topk1 <<<TK_BLOCKS, 256, 0, stream>>>(ws_s, ws_cand);
    k_final <<<1, 384, 0, stream>>>(ws_part, ws_cand, n_answ, o, temp_vid, out);
}

// Round 3
// 61.185 us; speedup vs baseline: 1.2365x; 1.2365x over previous
//
#include <hip/hip_runtime.h>
#include <cstdint>
#include <cstddef>

typedef unsigned long long u64;

// Problem constants (from reference)
constexpr int N    = 50000;   // library size
constexpr int D    = 768;     // vision dim
constexpr int OD   = 384;     // option / answer dim
constexpr int TOPK = 25;

// K1 config: one 64-lane wave per row-pair
constexpr int K1_BLOCKS  = 2048;
constexpr int K1_THREADS = 256;                            // 4 waves
constexpr int WAVES_TOTAL = K1_BLOCKS * (K1_THREADS / 64); // 8192

// top-k phase-1 config: 64 single-wave blocks, keys in registers
constexpr int TK_BLOCKS = 64;
constexpr int TK_CHUNK  = 782;          // 64 * 782 = 50048 >= 50000
constexpr int KPT       = 13;           // keys per thread: 64*13 = 832 >= 782
constexpr int NCAND     = TK_BLOCKS * TOPK;  // 1600

// ---------------------------------------------------------------------------
// K1: per-row cosine score s[n] = clip(dot(v,f_n)/(|v||f_n|), 0, 1),
//     plus per-block partial sums of exp(s[n]) (softmax denominator).
// One wave per TWO rows per iteration: 6 dwordx4 loads in flight, two
// independent reduction chains (ILP), rows read as 3 KB contiguous float4.
// ---------------------------------------------------------------------------
__global__ __launch_bounds__(K1_THREADS)
void k_scores(const float* __restrict__ v,
              const float* __restrict__ n_feats,
              float* __restrict__ s_out,
              float* __restrict__ part_out)
{
    const int lane  = threadIdx.x & 63;
    const int wib   = threadIdx.x >> 6;           // wave in block (0..3)
    const int gwave = blockIdx.x * 4 + wib;       // global wave id

    const float4* v4 = reinterpret_cast<const float4*>(v);
    const float4 va = v4[lane];
    const float4 vb = v4[lane + 64];
    const float4 vc = v4[lane + 128];

    // |v| (identical in every lane after butterfly)
    float vsq = 0.f;
    vsq = fmaf(va.x, va.x, vsq); vsq = fmaf(va.y, va.y, vsq);
    vsq = fmaf(va.z, va.z, vsq); vsq = fmaf(va.w, va.w, vsq);
    vsq = fmaf(vb.x, vb.x, vsq); vsq = fmaf(vb.y, vb.y, vsq);
    vsq = fmaf(vb.z, vb.z, vsq); vsq = fmaf(vb.w, vb.w, vsq);
    vsq = fmaf(vc.x, vc.x, vsq); vsq = fmaf(vc.y, vc.y, vsq);
    vsq = fmaf(vc.z, vc.z, vsq); vsq = fmaf(vc.w, vc.w, vsq);
    #pragma unroll
    for (int off = 32; off; off >>= 1) vsq += __shfl_xor(vsq, off);
    const float inv_vn = 1.0f / fmaxf(sqrtf(vsq), 1e-12f);

    float esum = 0.f;
    for (int r = 2 * gwave; r < N; r += 2 * WAVES_TOTAL) {
        const bool two = (r + 1) < N;
        const float4* f0 = reinterpret_cast<const float4*>(n_feats + (size_t)r * D);
        const float4* f1 = reinterpret_cast<const float4*>(n_feats + (size_t)(two ? r + 1 : r) * D);

        // issue all 6 loads up front
        const float4 a0 = f0[lane];
        const float4 a1 = f0[lane + 64];
        const float4 a2 = f0[lane + 128];
        const float4 b0 = f1[lane];
        const float4 b1 = f1[lane + 64];
        const float4 b2 = f1[lane + 128];

        float dA = 0.f, nA = 0.f, dB = 0.f, nB = 0.f;
        dA = fmaf(a0.x, va.x, dA); nA = fmaf(a0.x, a0.x, nA);
        dB = fmaf(b0.x, va.x, dB); nB = fmaf(b0.x, b0.x, nB);
        dA = fmaf(a0.y, va.y, dA); nA = fmaf(a0.y, a0.y, nA);
        dB = fmaf(b0.y, va.y, dB); nB = fmaf(b0.y, b0.y, nB);
        dA = fmaf(a0.z, va.z, dA); nA = fmaf(a0.z, a0.z, nA);
        dB = fmaf(b0.z, va.z, dB); nB = fmaf(b0.z, b0.z, nB);
        dA = fmaf(a0.w, va.w, dA); nA = fmaf(a0.w, a0.w, nA);
        dB = fmaf(b0.w, va.w, dB); nB = fmaf(b0.w, b0.w, nB);
        dA = fmaf(a1.x, vb.x, dA); nA = fmaf(a1.x, a1.x, nA);
        dB = fmaf(b1.x, vb.x, dB); nB = fmaf(b1.x, b1.x, nB);
        dA = fmaf(a1.y, vb.y, dA); nA = fmaf(a1.y, a1.y, nA);
        dB = fmaf(b1.y, vb.y, dB); nB = fmaf(b1.y, b1.y, nB);
        dA = fmaf(a1.z, vb.z, dA); nA = fmaf(a1.z, a1.z, nA);
        dB = fmaf(b1.z, vb.z, dB); nB = fmaf(b1.z, b1.z, nB);
        dA = fmaf(a1.w, vb.w, dA); nA = fmaf(a1.w, a1.w, nA);
        dB = fmaf(b1.w, vb.w, dB); nB = fmaf(b1.w, b1.w, nB);
        dA = fmaf(a2.x, vc.x, dA); nA = fmaf(a2.x, a2.x, nA);
        dB = fmaf(b2.x, vc.x, dB); nB = fmaf(b2.x, b2.x, nB);
        dA = fmaf(a2.y, vc.y, dA); nA = fmaf(a2.y, a2.y, nA);
        dB = fmaf(b2.y, vc.y, dB); nB = fmaf(b2.y, b2.y, nB);
        dA = fmaf(a2.z, vc.z, dA); nA = fmaf(a2.z, a2.z, nA);
        dB = fmaf(b2.z, vc.z, dB); nB = fmaf(b2.z, b2.z, nB);
        dA = fmaf(a2.w, vc.w, dA); nA = fmaf(a2.w, a2.w, nA);
        dB = fmaf(b2.w, vc.w, dB); nB = fmaf(b2.w, b2.w, nB);

        #pragma unroll
        for (int off = 32; off; off >>= 1) {
            dA += __shfl_xor(dA, off);
            nA += __shfl_xor(nA, off);
            dB += __shfl_xor(dB, off);
            nB += __shfl_xor(nB, off);
        }

        float sA = dA * inv_vn / fmaxf(sqrtf(nA), 1e-12f);
        sA = fminf(fmaxf(sA, 0.f), 1.f);
        float sB = dB * inv_vn / fmaxf(sqrtf(nB), 1e-12f);
        sB = fminf(fmaxf(sB, 0.f), 1.f);
        if (lane == 0) {
            s_out[r] = sA;
            if (two) s_out[r + 1] = sB;
        }
        esum += expf(sA);
        if (two) esum += expf(sB);
    }

    __shared__ float wsum[4];
    if (lane == 0) wsum[wib] = esum;
    __syncthreads();
    if (threadIdx.x == 0)
        part_out[blockIdx.x] = (wsum[0] + wsum[1]) + (wsum[2] + wsum[3]);
}

// ---------------------------------------------------------------------------
// K2: per-chunk exact top-25, ONE WAVE per block, keys in registers only
// (compile-time indexed), zero __syncthreads. Key = (value_bits<<32)|(~idx):
// larger value wins, ties -> lower index (matches jax.lax.top_k). s >= 0
// (clipped) so float bits are integer-ordered. Output is sorted descending.
// ---------------------------------------------------------------------------
__global__ __launch_bounds__(64)
void k_topk1(const float* __restrict__ s_in,
             u64* __restrict__ cand)
{
    const int b    = blockIdx.x;
    const int base = b * TK_CHUNK;
    const int lane = threadIdx.x;

    u64 k[KPT];
    #pragma unroll
    for (int j = 0; j < KPT; ++j) {
        const int i = lane + 64 * j;
        u64 key = 0ull;
        if (i < TK_CHUNK) {
            const int g = base + i;
            if (g < N) {
                key = ((u64)__float_as_uint(s_in[g]) << 32) |
                      (u64)(0xFFFFFFFFu - (unsigned)g);
            }
        }
        k[j] = key;
    }

    for (int r = 0; r < TOPK; ++r) {
        u64 m = k[0];
        #pragma unroll
        for (int j = 1; j < KPT; ++j) m = (k[j] > m) ? k[j] : m;
        u64 w = m;
        #pragma unroll
        for (int off = 32; off; off >>= 1) {
            const u64 ow = __shfl_xor(w, off);
            w = (ow > w) ? ow : w;
        }
        if (lane == 0) cand[b * TOPK + r] = w;
        // winner-clear (keys are unique; at most one reg matches)
        #pragma unroll
        for (int j = 0; j < KPT; ++j) if (k[j] == w) k[j] = 0ull;
    }
}

// ---------------------------------------------------------------------------
// K3: single block, 256 threads.
//  (a) Z = sum of 2048 exp-partials (power-of-2 LDS tree, deterministic)
//  (b) 64-way merge of the 64 sorted top-25 lists on wave 0 only:
//      lane l owns list l; per round one u64 butterfly max, winner lane
//      advances its cursor (keys unique -> exactly one lane matches).
//  (c) oia[d] = sum_j w_j * n_answ[idx_j][d]
//  (d) scores[k] = dot(oia, o[k]) via power-of-2 LDS tree
// ---------------------------------------------------------------------------
__global__ __launch_bounds__(256)
void k_final(const float* __restrict__ part,
             const u64* __restrict__ cand,
             const float* __restrict__ n_answ,
             const float* __restrict__ o,
             const float* __restrict__ temp_vid,
             float* __restrict__ out)
{
    __shared__ u64   ck[NCAND];     // 12.8 KB
    __shared__ float red[256];
    __shared__ float oiash[OD];
    __shared__ float topw[TOPK];
    __shared__ int   topi[TOPK];
    __shared__ float zsh;

    const int tid  = threadIdx.x;
    const int lane = tid & 63;
    const int wib  = tid >> 6;

    // (a) softmax denominator Z
    float z = 0.f;
    for (int i = tid; i < K1_BLOCKS; i += 256) z += part[i];
    red[tid] = z;
    __syncthreads();
    for (int s = 128; s > 0; s >>= 1) {
        if (tid < s) red[tid] += red[tid + s];
        __syncthreads();
    }
    if (tid == 0) zsh = red[0];

    // stage candidates in LDS
    for (int i = tid; i < NCAND; i += 256) ck[i] = cand[i];
    __syncthreads();

    // (b) 64-way sorted-list merge on wave 0 (wave-synchronous, no barriers)
    if (wib == 0) {
        int cur = 0;
        u64 head = ck[lane * TOPK];       // every list has 25 real keys (chunk >= 25)
        for (int r = 0; r < TOPK; ++r) {
            u64 w = head;
            #pragma unroll
            for (int off = 32; off; off >>= 1) {
                const u64 ow = __shfl_xor(w, off);
                w = (ow > w) ? ow : w;
            }
            if (lane == 0) {
                topw[r] = expf(__uint_as_float((unsigned)(w >> 32)));
                topi[r] = (int)(0xFFFFFFFFu - (unsigned)(w & 0xFFFFFFFFu));
            }
            if (head == w) {              // exactly one lane
                ++cur;
                head = (cur < TOPK) ? ck[lane * TOPK + cur] : 0ull;
            }
        }
    }
    __syncthreads();

    // (c) oia gather: attention_j = exp(s_j)/Z * vid_gate;  vid_gate = 2*sigmoid(t)
    const float gate  = 2.f / (1.f + expf(-temp_vid[0]));
    const float scale = gate / zsh;
    for (int d = tid; d < OD; d += 256) {
        float acc = 0.f;
        #pragma unroll
        for (int j = 0; j < TOPK; ++j)
            acc = fmaf(topw[j] * scale, n_answ[(size_t)topi[j] * OD + d], acc);
        oiash[d] = acc;
    }
    __syncthreads();

    // (d) 3 dot products (power-of-2 tree)
    for (int kk = 0; kk < 3; ++kk) {
        float a = 0.f;
        for (int d = tid; d < OD; d += 256)
            a = fmaf(oiash[d], o[kk * OD + d], a);
        red[tid] = a;
        __syncthreads();
        for (int s = 128; s > 0; s >>= 1) {
            if (tid < s) red[tid] += red[tid + s];
            __syncthreads();
        }
        if (tid == 0) out[kk] = red[0];
        __syncthreads();
    }
}

// ---------------------------------------------------------------------------
extern "C" void kernel_launch(void* const* d_in, const int* in_sizes, int n_in,
                              void* d_out, int out_size, void* d_ws, size_t ws_size,
                              hipStream_t stream)
{
    // setup_inputs order:
    // 0 v, 1 n_feats, 2 aud, 3 n_auds, 4 ocr, 5 n_ocrs, 6 o, 7 n_answ,
    // 8 temp_vid, 9 temp_aud, 10 temp_ocr
    const float* v        = (const float*)d_in[0];
    const float* n_feats  = (const float*)d_in[1];
    const float* o        = (const float*)d_in[6];
    const float* n_answ   = (const float*)d_in[7];
    const float* temp_vid = (const float*)d_in[8];
    // aud/ocr branches are multiplied by exactly 0.0 in the reference -> skipped.
    float* out = (float*)d_out;

    char* ws = (char*)d_ws;
    float* ws_s   = (float*)(ws);            // 50000 f32 = 200000 B
    float* ws_part= (float*)(ws + 204800);   // 2048 f32  = 8192 B
    u64*   ws_cand= (u64*)  (ws + 215040);   // 1600 u64  = 12800 B

    k_scores<<<K1_BLOCKS, K1_THREADS, 0, stream>>>(v, n_feats, ws_s, ws_part);
    k_topk1 <<<TK_BLOCKS, 64, 0, stream>>>(ws_s, ws_cand);
    k_final <<<1, 256, 0, stream>>>(ws_part, ws_cand, n_answ, o, temp_vid, out);
}